// Round 1
// baseline (130.967 us; speedup 1.0000x reference)
//
#include <hip/hip_runtime.h>
#include <math.h>

#define BATCH 262144
#define N 8
#define BLK 256
#define NBLK (BATCH / BLK)   // 1024
#define STEEP 10.0f
#define INV_PI 0.31830988618379067f

__global__ __launch_bounds__(BLK) void diffsort_loss_kernel(
    const float* __restrict__ pred,
    const float* __restrict__ labels,
    const float* __restrict__ rank_ema,
    float* __restrict__ partial)
{
    const int row = blockIdx.x * BLK + threadIdx.x;

    // ---- vectorized row loads (8 floats = 2x float4 each) ----
    const float4* lp = (const float4*)(labels + (size_t)row * N);
    const float4* pp = (const float4*)(pred   + (size_t)row * N);
    float4 l0 = lp[0], l1 = lp[1];
    float4 p0 = pp[0], p1 = pp[1];
    float lab[N] = {l0.x, l0.y, l0.z, l0.w, l1.x, l1.y, l1.z, l1.w};
    float prd[N] = {p0.x, p0.y, p0.z, p0.w, p1.x, p1.y, p1.z, p1.w};

    // ---- rank_true[i]: position of element i in stable descending sort ----
    int rt[N];
#pragma unroll
    for (int i = 0; i < N; ++i) {
        int r = 0;
#pragma unroll
        for (int j = 0; j < N; ++j) {
            // strictly greater, or equal with smaller index (stable argsort of -labels)
            r += (lab[j] > lab[i]) || ((lab[j] == lab[i]) && (j < i));
        }
        rt[i] = r;
    }

    // ---- x = -(pred - rank_ema[rank_true]) ----
    float x[N];
#pragma unroll
    for (int i = 0; i < N; ++i)
        x[i] = rank_ema[rt[i]] - prd[i];

    // ---- odd-even diffsort network, tracking column-permutation P ----
    float P[N][N];
#pragma unroll
    for (int i = 0; i < N; ++i)
#pragma unroll
        for (int j = 0; j < N; ++j)
            P[i][j] = (i == j) ? 1.0f : 0.0f;

#pragma unroll
    for (int layer = 0; layer < N; ++layer) {
        const int start = layer & 1;
#pragma unroll
        for (int ia = 0; ia < N - 1; ++ia) {
            if ((ia & 1) != start) continue;   // compile-time pruned after unroll
            const int ib = ia + 1;
            const float a = x[ia], b = x[ib];
            const float alpha = atanf(STEEP * (b - a)) * INV_PI + 0.5f;
            const float oma = 1.0f - alpha;
            x[ia] = alpha * a + oma * b;
            x[ib] = oma * a + alpha * b;
#pragma unroll
            for (int i = 0; i < N; ++i) {
                const float ca = P[i][ia], cb = P[i][ib];
                P[i][ia] = alpha * ca + oma * cb;
                P[i][ib] = oma * ca + alpha * cb;
            }
        }
    }

    // ---- per-row CE sum: gt[i][j] = (rt[i] == j) ----
    float s = 0.0f;
#pragma unroll
    for (int i = 0; i < N; ++i) {
#pragma unroll
        for (int j = 0; j < N; ++j) {
            const float p = P[i][j];
            const float t = (rt[i] == j) ? logf(p) : log1pf(-p);
            s += fmaxf(t, -100.0f);
        }
    }

    // ---- wave (64) shuffle reduce, then block reduce to one partial ----
#pragma unroll
    for (int off = 32; off > 0; off >>= 1)
        s += __shfl_down(s, off);

    __shared__ float wsum[BLK / 64];
    const int lane = threadIdx.x & 63;
    const int wid  = threadIdx.x >> 6;
    if (lane == 0) wsum[wid] = s;
    __syncthreads();
    if (threadIdx.x == 0) {
        float t = 0.0f;
#pragma unroll
        for (int w = 0; w < BLK / 64; ++w) t += wsum[w];
        partial[blockIdx.x] = t;
    }
}

__global__ __launch_bounds__(256) void reduce_partials(
    const float* __restrict__ partial, float* __restrict__ out)
{
    float s = 0.0f;
    for (int i = threadIdx.x; i < NBLK; i += 256)
        s += partial[i];
#pragma unroll
    for (int off = 32; off > 0; off >>= 1)
        s += __shfl_down(s, off);

    __shared__ float wsum[4];
    const int lane = threadIdx.x & 63;
    const int wid  = threadIdx.x >> 6;
    if (lane == 0) wsum[wid] = s;
    __syncthreads();
    if (threadIdx.x == 0) {
        const float tot = wsum[0] + wsum[1] + wsum[2] + wsum[3];
        // loss = -sum / (B * n * n)
        out[0] = -tot * (1.0f / 16777216.0f);
    }
}

extern "C" void kernel_launch(void* const* d_in, const int* in_sizes, int n_in,
                              void* d_out, int out_size, void* d_ws, size_t ws_size,
                              hipStream_t stream)
{
    const float* pred     = (const float*)d_in[0];
    const float* labels   = (const float*)d_in[1];
    const float* rank_ema = (const float*)d_in[2];
    float* out     = (float*)d_out;
    float* partial = (float*)d_ws;   // needs NBLK*4 = 4 KiB of scratch

    diffsort_loss_kernel<<<NBLK, BLK, 0, stream>>>(pred, labels, rank_ema, partial);
    reduce_partials<<<1, 256, 0, stream>>>(partial, out);
}

// Round 2
// 78.354 us; speedup vs baseline: 1.6715x; 1.6715x over previous
//
#include <hip/hip_runtime.h>
#include <math.h>

#define BATCH 262144
#define N 8
#define BLK 256
#define NBLK (BATCH / BLK)   // 1024
#define NCMP 28              // odd-even network on 8 elems: 4+3+4+3+4+3+4+3

// alpha(z) = 0.5 + atan(z)/pi  (Cauchy CDF), custom minimax:
// atan(t) ~ t*P(t^2) on [0,1], |err| ~ 1e-6; arg-reduce via rcp for |z|>1.
// Small-alpha error is RELATIVE (rcp 1ulp + poly abs err on small result),
// so log-domain loss terms stay accurate.
__device__ __forceinline__ float cauchy_alpha(float z) {
    float az  = __builtin_fabsf(z);
    bool  big = az > 1.0f;
    float inv = __builtin_amdgcn_rcpf(az);
    float t   = big ? inv : az;
    float t2  = t * t;
    float p   = -0.01172120f;
    p = __builtin_fmaf(p, t2, 0.05265332f);
    p = __builtin_fmaf(p, t2, -0.11643287f);
    p = __builtin_fmaf(p, t2, 0.19354346f);
    p = __builtin_fmaf(p, t2, -0.33262347f);
    p = __builtin_fmaf(p, t2, 0.99997726f);
    float at = p * t;                                   // atan(t)
    float r  = big ? (1.5707963267948966f - at) : at;   // atan(|z|)
    float sr = __builtin_copysignf(r, z);               // atan(z)
    return __builtin_fmaf(sr, 0.31830988618379067f, 0.5f);
}

__global__ __launch_bounds__(BLK, 2) void diffsort_loss_kernel(
    const float* __restrict__ pred,
    const float* __restrict__ labels,
    const float* __restrict__ rank_ema,
    float* __restrict__ partial)
{
    const int row = blockIdx.x * BLK + threadIdx.x;

    // ---- vectorized row loads ----
    const float4* lp = (const float4*)(labels + (size_t)row * N);
    const float4* pp = (const float4*)(pred   + (size_t)row * N);
    float4 l0 = lp[0], l1 = lp[1];
    float4 p0 = pp[0], p1 = pp[1];
    float lab[N] = {l0.x, l0.y, l0.z, l0.w, l1.x, l1.y, l1.z, l1.w};
    float prd[N] = {p0.x, p0.y, p0.z, p0.w, p1.x, p1.y, p1.z, p1.w};

    // rank_ema is tiny & uniform -> scalar-cached loads
    const float4* ep = (const float4*)rank_ema;
    float4 e0 = ep[0], e1 = ep[1];

    // ---- rank_true via pairwise comparisons (stable argsort of -labels) ----
    int rt[N];
#pragma unroll
    for (int i = 0; i < N; ++i) rt[i] = 0;
#pragma unroll
    for (int i = 0; i < N; ++i)
#pragma unroll
        for (int j = i + 1; j < N; ++j) {
            // j>i: counts toward rt[i] iff lab[j] strictly greater;
            // toward rt[j] iff lab[i] >= lab[j] (tie goes to lower index)
            bool c = lab[j] > lab[i];
            rt[i] += c ? 1 : 0;
            rt[j] += c ? 0 : 1;
        }

    // ---- x = rank_ema[rt] - pred  (= -shifted), select tree (register-only) ----
    float x[N];
#pragma unroll
    for (int i = 0; i < N; ++i) {
        const int k = rt[i];
        float g = (k & 4) ? ((k & 2) ? ((k & 1) ? e1.w : e1.z)
                                     : ((k & 1) ? e1.y : e1.x))
                          : ((k & 2) ? ((k & 1) ? e0.w : e0.z)
                                     : ((k & 1) ? e0.y : e0.x));
        x[i] = g - prd[i];
    }

    // ---- odd-even network on x, record the 28 alphas ----
    float al[NCMP];
    {
        int ac = 0;
#pragma unroll
        for (int layer = 0; layer < N; ++layer) {
#pragma unroll
            for (int ia = (layer & 1); ia < N - 1; ia += 2) {
                const int ib = ia + 1;
                const float a = x[ia], b = x[ib];
                const float alpha = cauchy_alpha(10.0f * (b - a));
                al[ac++] = alpha;
                const float d = a - b;
                x[ia] = __builtin_fmaf(alpha, d, b);   // alpha*a + (1-alpha)*b
                x[ib] = __builtin_fmaf(-alpha, d, a);  // (1-alpha)*a + alpha*b
            }
        }
    }

    // ---- P rows evolve independently through the same column ops:
    //      row i of P = e_i^T * C1*...*C28. Simulate one row at a time
    //      (8 live floats instead of 64) and consume its loss terms. ----
    float s = 0.0f;
#pragma unroll
    for (int i = 0; i < N; ++i) {
        float r[N];
#pragma unroll
        for (int j = 0; j < N; ++j) r[j] = (i == j) ? 1.0f : 0.0f;

        int ac = 0;
#pragma unroll
        for (int layer = 0; layer < N; ++layer) {
#pragma unroll
            for (int ia = (layer & 1); ia < N - 1; ia += 2) {
                const int ib = ia + 1;
                const float alpha = al[ac++];
                const float ca = r[ia], cb = r[ib];
                const float d  = ca - cb;
                r[ia] = __builtin_fmaf(alpha, d, cb);
                r[ib] = __builtin_fmaf(-alpha, d, ca);
            }
        }

        // gt row i is one-hot at column rt[i]:
        //   hot term:  clip(log p, -100)
        //   others:    sum log1p(-p) == log(prod(1-p))  (per-entry clip can't
        //   engage: P row-stochastic -> at most one entry near 1, and alphas
        //   never round to 0/1 for |z| <~ 300)
        const int hj = rt[i];
        float hot = 0.0f, prodq = 1.0f;
#pragma unroll
        for (int j = 0; j < N; ++j) {
            const bool ish = (hj == j);
            const float q = fmaxf(1.0f - r[j], 1e-38f);
            prodq *= ish ? 1.0f : q;
            hot    = ish ? r[j] : hot;
        }
        s += fmaxf(__logf(hot), -100.0f);
        s += __logf(fmaxf(prodq, 1e-38f));
    }

    // ---- wave(64) shuffle reduce -> block partial ----
#pragma unroll
    for (int off = 32; off > 0; off >>= 1)
        s += __shfl_down(s, off);

    __shared__ float wsum[BLK / 64];
    const int lane = threadIdx.x & 63;
    const int wid  = threadIdx.x >> 6;
    if (lane == 0) wsum[wid] = s;
    __syncthreads();
    if (threadIdx.x == 0) {
        float t = 0.0f;
#pragma unroll
        for (int w = 0; w < BLK / 64; ++w) t += wsum[w];
        partial[blockIdx.x] = t;
    }
}

__global__ __launch_bounds__(256) void reduce_partials(
    const float* __restrict__ partial, float* __restrict__ out)
{
    float s = 0.0f;
    for (int i = threadIdx.x; i < NBLK; i += 256)
        s += partial[i];
#pragma unroll
    for (int off = 32; off > 0; off >>= 1)
        s += __shfl_down(s, off);

    __shared__ float wsum[4];
    const int lane = threadIdx.x & 63;
    const int wid  = threadIdx.x >> 6;
    if (lane == 0) wsum[wid] = s;
    __syncthreads();
    if (threadIdx.x == 0) {
        const float tot = wsum[0] + wsum[1] + wsum[2] + wsum[3];
        // loss = -sum / (B * n * n) = -sum / 16777216
        out[0] = -tot * (1.0f / 16777216.0f);
    }
}

extern "C" void kernel_launch(void* const* d_in, const int* in_sizes, int n_in,
                              void* d_out, int out_size, void* d_ws, size_t ws_size,
                              hipStream_t stream)
{
    const float* pred     = (const float*)d_in[0];
    const float* labels   = (const float*)d_in[1];
    const float* rank_ema = (const float*)d_in[2];
    float* out     = (float*)d_out;
    float* partial = (float*)d_ws;   // NBLK*4 = 4 KiB scratch

    diffsort_loss_kernel<<<NBLK, BLK, 0, stream>>>(pred, labels, rank_ema, partial);
    reduce_partials<<<1, 256, 0, stream>>>(partial, out);
}